// Round 8
// baseline (159.207 us; speedup 1.0000x reference)
//
#include <hip/hip_runtime.h>
#include <hip/hip_bf16.h>

#define N_NODES 50000
#define N_EDGES 800000
#define D_IN 96
#define D_OUT 128
#define CAP 64              // deg ~ Poisson(16); P(deg>=64) ~ e^-41 -> no drops

// XCD-sliced fill (R5): 8 slices x 6250 nodes; block group g = blockIdx&7
// lands on XCD g (round-robin heuristic); bucket/cursor lines for a slice are
// written from ONE XCD -> merge in its L2 instead of churning HBM.
#define SLICES 8
#define NODES_PER_SLICE 6250
#define GROUP_BLOCKS 256
#define FILL_BLOCKS (SLICES * GROUP_BLOCKS)         // 2048
#define EDGES_PER_BLOCK 3125                        // 3125*256 = 800000 exactly

#define CONV_THREADS (N_NODES * 12)                 // 600000 (one per 8-elem chunk)
#define CONV_BLOCKS ((CONV_THREADS + 255) / 256)    // 2344
#define WCONV_BLOCKS 12                             // 128*24 = 3072 tasks

// fused agg+gemm: 64 nodes/block, 4 waves x 16-node MFMA tiles
#define NPB 64
#define AG_BLOCKS ((N_NODES + NPB - 1) / NPB)       // 782
#define AH_PITCH 104        // u16/row (96 + 8 pad); 208 B rows, b128-aligned

// ws layout (256B-aligned sections)
#define WS_BUCKET 200192
#define WS_XH     (WS_BUCKET + 6400000)             // 6600192
#define WS_WFRAG  (WS_XH + 9600000)                 // 16200192
#define WS_XQ     (WS_WFRAG + 49152)                // 16249344

typedef unsigned short u16;
typedef unsigned char u8;
typedef __attribute__((ext_vector_type(8))) short short8;   // 8 x bf16 (4 VGPRs)
typedef __attribute__((ext_vector_type(4))) float f32x4;
typedef __attribute__((ext_vector_type(2))) float f32x2;

#if defined(__has_builtin)
#if __has_builtin(__builtin_amdgcn_cvt_pk_f32_fp8) && __has_builtin(__builtin_amdgcn_cvt_pk_fp8_f32)
#define HAVE_FP8_CVT 1
#endif
#endif

__device__ __forceinline__ u16 f2bf(float f) {
    unsigned u = __float_as_uint(f);
    unsigned r = (u + 0x7FFFu + ((u >> 16) & 1u)) >> 16;   // RNE
    return (u16)r;
}
__device__ __forceinline__ float bf2f(u16 h) {
    return __uint_as_float(((unsigned)h) << 16);
}

// ---- fp8 e4m3fn helpers (HW cvt when available; manual fallback) ----------
__device__ __forceinline__ unsigned pack4_e4m3(float a, float b, float c, float d) {
#ifdef HAVE_FP8_CVT
    int r = 0;
    r = __builtin_amdgcn_cvt_pk_fp8_f32(a, b, r, false);   // bytes 0,1
    r = __builtin_amdgcn_cvt_pk_fp8_f32(c, d, r, true);    // bytes 2,3
    return (unsigned)r;
#else
    float v[4] = {a, b, c, d};
    unsigned r = 0;
    for (int i = 0; i < 4; i++) {
        unsigned u = __float_as_uint(v[i]);
        unsigned s = (u >> 24) & 0x80u;
        unsigned aa = u & 0x7FFFFFFFu;
        unsigned enc;
        if (aa >= 0x43E00000u) enc = s | 0x7Eu;                 // clamp to 448
        else if (aa < 0x3C800000u) {                            // < 2^-6: subnormal
            int m = (int)rintf(__uint_as_float(aa) * 512.0f);
            enc = s | (unsigned)(m > 8 ? 8 : m);                // m==8 -> 0x08 = 2^-6
        } else {
            unsigned rr = aa + 0x0007FFFFu + ((aa >> 20) & 1u); // RNE to 3 man bits
            int ee = (int)(rr >> 23) - 120;
            unsigned man = (rr >> 20) & 7u;
            enc = (ee >= 16) ? (s | 0x7Eu) : (s | ((unsigned)ee << 3) | man);
        }
        r |= enc << (8 * i);
    }
    return r;
#endif
}

__device__ __forceinline__ f32x2 unpack2_lo(unsigned dw) {
#ifdef HAVE_FP8_CVT
    return __builtin_amdgcn_cvt_pk_f32_fp8((int)dw, false);
#else
    f32x2 r;
    for (int i = 0; i < 2; i++) {
        unsigned v = (dw >> (8 * i)) & 0xFFu;
        unsigned s = (v & 0x80u) << 24;
        unsigned e = (v >> 3) & 15u, m = v & 7u;
        float f = (e == 0) ? ((float)m * (1.0f / 512.0f))
                           : __uint_as_float(((e + 120u) << 23) | (m << 20));
        f = __uint_as_float(__float_as_uint(f) | s);
        if (i == 0) r.x = f; else r.y = f;
    }
    return r;
#endif
}
__device__ __forceinline__ f32x2 unpack2_hi(unsigned dw) {
#ifdef HAVE_FP8_CVT
    return __builtin_amdgcn_cvt_pk_f32_fp8((int)dw, true);
#else
    return unpack2_lo(dw >> 16);
#endif
}

// ---------------------------------------------------------------------------
// K1: heterogeneous grid.
//   [0, FILL_BLOCKS): XCD-sliced edge binning.
//   [+CONV_BLOCKS): xh = bf16(x) AND xq = fp8_e4m3(x), row-major.
//   [+WCONV_BLOCKS): Wfrag = bf16 B-fragment layout of [Wl|Wr].
// fill is store-transaction bound with idle pipes; conversions ride free.
// ---------------------------------------------------------------------------
__global__ __launch_bounds__(256) void sage_fill_conv(
    const int* __restrict__ src,
    const int* __restrict__ dst,
    const float* __restrict__ x,
    const float* __restrict__ Wl,
    const float* __restrict__ Wr,
    int* __restrict__ cursor,
    u16* __restrict__ bucket,
    u16* __restrict__ xh,
    u8*  __restrict__ xq,
    u16* __restrict__ Wfrag)
{
    const int b = blockIdx.x;
    if (b < FILL_BLOCKS) {
        const int slice = b & 7;
        const int gb = b >> 3;
        const int lo = slice * NODES_PER_SLICE;
        const int hi = lo + NODES_PER_SLICE;
        const int e0 = gb * EDGES_PER_BLOCK;
        int e1 = e0 + EDGES_PER_BLOCK;
        if (e1 > N_EDGES) e1 = N_EDGES;
        for (int e = e0 + (int)threadIdx.x; e < e1; e += 256) {
            int d = dst[e];
            int s = src[e];
            if (d >= lo && d < hi) {
                int pos = atomicAdd(&cursor[d], 1);
                if (pos < CAP) bucket[(size_t)d * CAP + pos] = (u16)s;
            }
        }
    } else if (b < FILL_BLOCKS + CONV_BLOCKS) {
        unsigned t = (unsigned)(b - FILL_BLOCKS) * 256u + threadIdx.x;
        if (t >= (unsigned)CONV_THREADS) return;
        unsigned n = t / 12u;
        unsigned c8 = t - n * 12u;
        const float* p = x + (size_t)n * D_IN + c8 * 8u;
        float v[8];
#pragma unroll
        for (int i = 0; i < 8; i++) v[i] = p[i];
        short8 hv;
#pragma unroll
        for (int i = 0; i < 8; i++) hv[i] = (short)f2bf(v[i]);
        *(short8*)(xh + (size_t)n * D_IN + c8 * 8u) = hv;
        uint2 q;
        q.x = pack4_e4m3(v[0], v[1], v[2], v[3]);
        q.y = pack4_e4m3(v[4], v[5], v[6], v[7]);
        *(uint2*)(xq + (size_t)n * D_IN + c8 * 8u) = q;
    } else {
        // W -> bf16 B-fragments: 128 j x 24 chunks (12 Wl + 12 Wr)
        int idx = (b - FILL_BLOCKS - CONV_BLOCKS) * 256 + (int)threadIdx.x; // <3072
        int j = idx / 24;
        int c8 = idx - j * 24;
        int kc = c8 >> 2;
        int quad = c8 & 3;
        const float* wsrc = (c8 < 12) ? (Wl + (size_t)j * D_IN + c8 * 8)
                                      : (Wr + (size_t)j * D_IN + (c8 - 12) * 8);
        int jt = j >> 4;
        int col = j & 15;
        short8 v;
#pragma unroll
        for (int i = 0; i < 8; i++) v[i] = (short)f2bf(wsrc[i]);
        *(short8*)(Wfrag + (((jt * 6 + kc) * 64) + col + 16 * quad) * 8) = v;
    }
}

// ---------------------------------------------------------------------------
// K2 (fused): fp8 mean-aggregation into LDS Ah (bf16), then MFMA GEMM.
// Phase A: 768 tasks = (node m:64) x (chunk c6:6 of 16 fp8) x (half h:2).
//   Each half loads one b128 of 8 bucket indices + 8 gathers (uint4 = 16 fp8)
//   in flight; HW cvt_pk_f32_fp8 decode + v_pk_add_f32 accumulate.
//   Halves are adjacent lanes -> pair-combine via __shfl_xor(.,1), each lane
//   finalizes 8 elems (x invd, ->bf16) into Ah.
// Phase B: per-wave 16-node MFMA tile (R7, verified): A kc0..2 from Ah,
//   kc3..5 from xh (bf16 self term); B-frags coalesced from global Wfrag.
// LDS = 13.3 KB only.
// ---------------------------------------------------------------------------
__global__ __launch_bounds__(256) void sage_agg_gemm(
    const u16* __restrict__ xh,
    const u8*  __restrict__ xq,
    const int* __restrict__ cursor,
    const u16* __restrict__ bucket,
    const u16* __restrict__ Wfrag,
    const float* __restrict__ bl,
    float* __restrict__ out)
{
    __shared__ u16 Ah[NPB * AH_PITCH];      // 13312 B

    const int tid = threadIdx.x;
    const int n0 = blockIdx.x * NPB;

    // ---- phase A ----
#pragma unroll
    for (int rep = 0; rep < 3; rep++) {
        int task = rep * 256 + tid;          // 0..767
        int m = task / 12;
        int sub = task - m * 12;
        int c6 = sub >> 1;                   // 16-elem chunk 0..5
        int h = sub & 1;                     // half: lanes pair (tid, tid^1)
        int n = n0 + m;

        f32x2 acc2[8];
#pragma unroll
        for (int i = 0; i < 8; i++) acc2[i] = (f32x2){0.0f, 0.0f};
        float invd = 0.0f;

        if (n < N_NODES) {
            int deg = cursor[n];
            int degc = deg < CAP ? deg : CAP;
            const u16* brow = bucket + (size_t)n * CAP;
            const u8* xbase = xq + (unsigned)c6 * 16u;

            for (int base = h * 8; base < degc; base += 16) {
                short8 id = *(const short8*)(brow + base);   // 8 idx, one b128
                int cnt = degc - base; cnt = cnt > 8 ? 8 : cnt;
                uint4 w[8];
#pragma unroll
                for (int q = 0; q < 8; q++) {
                    if (q < cnt) {
                        unsigned s = (u16)id[q];
                        w[q] = *(const uint4*)(xbase + s * 96u);
                    } else {
                        w[q] = (uint4){0u, 0u, 0u, 0u};      // fp8 0 -> 0.0f
                    }
                }
#pragma unroll
                for (int q = 0; q < 8; q++) {
                    acc2[0] += unpack2_lo(w[q].x);  acc2[1] += unpack2_hi(w[q].x);
                    acc2[2] += unpack2_lo(w[q].y);  acc2[3] += unpack2_hi(w[q].y);
                    acc2[4] += unpack2_lo(w[q].z);  acc2[5] += unpack2_hi(w[q].z);
                    acc2[6] += unpack2_lo(w[q].w);  acc2[7] += unpack2_hi(w[q].w);
                }
            }
            invd = 1.0f / fmaxf((float)deg, 1.0f);
        }

        // pair-combine: this lane keeps elems [h*8, h*8+8) = acc2[h*4 .. +4)
        short8 o;
#pragma unroll
        for (int i = 0; i < 4; i++) {
            f32x2 mine = acc2[h * 4 + i];
            f32x2 send = acc2[(1 - h) * 4 + i];
            float rx = __shfl_xor(send.x, 1);
            float ry = __shfl_xor(send.y, 1);
            o[2 * i]     = (short)f2bf((mine.x + rx) * invd);
            o[2 * i + 1] = (short)f2bf((mine.y + ry) * invd);
        }
        *(short8*)(Ah + m * AH_PITCH + c6 * 16 + h * 8) = o;
    }
    __syncthreads();

    // ---- phase B: 16-node MFMA tile per wave ----
    const int wave = tid >> 6;
    const int lane = tid & 63;
    const int m16 = lane & 15;
    const int quad = lane >> 4;
    const int tilebase = n0 + wave * 16;
    if (tilebase >= N_NODES) return;         // single barrier already passed

    int nn = tilebase + m16;
    nn = nn < N_NODES ? nn : N_NODES - 1;    // clamp A-row source (store guarded)

    const u16* arow = Ah + (wave * 16 + m16) * AH_PITCH + quad * 8;
    const u16* xrow = xh + (size_t)nn * D_IN + quad * 8;
    short8 a[6];
#pragma unroll
    for (int kc = 0; kc < 3; kc++) a[kc]     = *(const short8*)(arow + kc * 32);
#pragma unroll
    for (int kc = 0; kc < 3; kc++) a[3 + kc] = *(const short8*)(xrow + kc * 32);

#pragma unroll
    for (int jt = 0; jt < 8; jt++) {
        f32x4 acc = {0.0f, 0.0f, 0.0f, 0.0f};
#pragma unroll
        for (int kc = 0; kc < 6; kc++) {
            short8 bfrag = *(const short8*)(Wfrag + ((jt * 6 + kc) * 64 + lane) * 8);
            acc = __builtin_amdgcn_mfma_f32_16x16x32_bf16(a[kc], bfrag, acc, 0, 0, 0);
        }
        const int j = jt * 16 + m16;         // col = lane&15
        const float bj = bl[j];
#pragma unroll
        for (int r = 0; r < 4; r++) {
            int row = quad * 4 + r;
            int n = tilebase + row;
            if (n < N_NODES)
                out[(size_t)n * D_OUT + j] = fmaxf(acc[r] + bj, 0.0f);
        }
    }
}

extern "C" void kernel_launch(void* const* d_in, const int* in_sizes, int n_in,
                              void* d_out, int out_size, void* d_ws, size_t ws_size,
                              hipStream_t stream) {
    const float* x   = (const float*)d_in[0];
    const int* eidx  = (const int*)d_in[1];
    const float* Wl  = (const float*)d_in[2];
    const float* bl  = (const float*)d_in[3];
    const float* Wr  = (const float*)d_in[4];
    float* out = (float*)d_out;

    const int* src = eidx;                // edge_index[0]
    const int* dst = eidx + N_EDGES;      // edge_index[1]

    char* ws = (char*)d_ws;
    int* cursor = (int*)ws;
    u16* bucket = (u16*)(ws + WS_BUCKET);
    u16* xh     = (u16*)(ws + WS_XH);
    u16* Wfrag  = (u16*)(ws + WS_WFRAG);
    u8*  xq     = (u8*)(ws + WS_XQ);

    hipMemsetAsync(cursor, 0, N_NODES * sizeof(int), stream);

    {
        dim3 grid(FILL_BLOCKS + CONV_BLOCKS + WCONV_BLOCKS);   // 4404
        sage_fill_conv<<<grid, 256, 0, stream>>>(src, dst, x, Wl, Wr,
                                                 cursor, bucket, xh, xq, Wfrag);
    }
    {
        dim3 grid(AG_BLOCKS);                                  // 782
        sage_agg_gemm<<<grid, 256, 0, stream>>>(xh, xq, cursor, bucket,
                                                Wfrag, bl, out);
    }
}